// Round 1
// baseline (1724.558 us; speedup 1.0000x reference)
//
#include <hip/hip_runtime.h>

// Problem constants
// B=256, N=196, C=256, H=8, KD=32, VD=64, Q=49, R=14
// scores scale = 32^-0.5

constexpr int TB = 256;

__global__ __launch_bounds__(256, 1)
void levit_fused_attn(const float* __restrict__ x,
                      const float* __restrict__ kv_w, const float* __restrict__ kv_g,
                      const float* __restrict__ kv_b, const float* __restrict__ kv_m,
                      const float* __restrict__ kv_v,
                      const float* __restrict__ q_w, const float* __restrict__ q_g,
                      const float* __restrict__ q_b, const float* __restrict__ q_m,
                      const float* __restrict__ q_v,
                      const float* __restrict__ attn_bias,
                      float* __restrict__ attn_out)
{
    constexpr int XSTR = 33;   // staging stride (conflict-free for scalar reads)
    constexpr int KSTR = 36;   // kbuf row stride (float4-aligned, conflict-free)
    constexpr int VSTR = 64;   // vbuf row stride (float4-aligned)
    constexpr int QSTR = 36;   // qbuf row stride
    constexpr int SSTR = 200;  // scores row stride

    __shared__ float kbuf[196 * KSTR];             // 28224 B
    __shared__ float vbuf[196 * VSTR];             // 50176 B
    __shared__ float qbuf[49 * QSTR];              // 7056 B
    __shared__ float rstat[64];                    // 1/rowsum
    __shared__ float un[224 * XSTR + 96 * XSTR];   // union: stage area / scores (42240 B)

    const int t = threadIdx.x;
    const int b = blockIdx.x;   // batch (b-major => same-b head blocks share XCD L2)
    const int h = blockIdx.y;   // head

    // ---------------- Phase 0: q = linear_norm(xq, q_w) -> qbuf[49][32]
    {
        float* xq_s = un;               // [64][XSTR] rows >=49 zero
        float* qw_s = un + 64 * XSTR;   // [32][XSTR]
        const int dt = t & 15;          // d = 2*dt, 2*dt+1
        const int qt = t >> 4;          // 0..15
        float acc[4][2] = {};
        for (int kc = 0; kc < 256; kc += 32) {
            __syncthreads();
            for (int f = t; f < 64 * 32; f += TB) {
                int qi = f >> 5, c = f & 31;
                float v = 0.f;
                if (qi < 49) {
                    int nrow = (qi / 7) * 28 + (qi % 7) * 2;   // stride-2 subsample of 14x14
                    v = x[(b * 196 + nrow) * 256 + kc + c];
                }
                xq_s[qi * XSTR + c] = v;
            }
            for (int f = t; f < 32 * 32; f += TB) {
                int d = f >> 5, c = f & 31;
                qw_s[d * XSTR + c] = q_w[(h * 32 + d) * 256 + kc + c];
            }
            __syncthreads();
            #pragma unroll 4
            for (int c = 0; c < 32; ++c) {
                float w0 = qw_s[(2 * dt) * XSTR + c];
                float w1 = qw_s[(2 * dt + 1) * XSTR + c];
                #pragma unroll
                for (int k = 0; k < 4; ++k) {
                    float xv = xq_s[(qt + 16 * k) * XSTR + c];
                    acc[k][0] += xv * w0;
                    acc[k][1] += xv * w1;
                }
            }
        }
        #pragma unroll
        for (int j = 0; j < 2; ++j) {
            int col = h * 32 + 2 * dt + j;
            float iv = q_g[col] * rsqrtf(q_v[col] + 1e-5f);
            float be = q_b[col] - q_m[col] * iv;
            #pragma unroll
            for (int k = 0; k < 4; ++k) {
                int qi = qt + 16 * k;
                if (qi < 49) qbuf[qi * QSTR + 2 * dt + j] = acc[k][j] * iv + be;
            }
        }
    }

    // ---------------- Phase 1: kv = linear_norm(x, kv_w) -> kbuf[196][32], vbuf[196][64]
    {
        float* xs = un;                 // [224][XSTR], rows >=196 zero
        float* ws = un + 224 * XSTR;    // [96][XSTR]
        const int jt = t & 7;           // j = jt*12 + jj
        const int nt = t >> 3;          // n = nt + 32*k
        float acc[7][12] = {};
        for (int kc = 0; kc < 256; kc += 32) {
            __syncthreads();
            for (int f = t; f < 224 * 32; f += TB) {
                int n = f >> 5, c = f & 31;
                xs[n * XSTR + c] = (n < 196) ? x[(b * 196 + n) * 256 + kc + c] : 0.f;
            }
            for (int f = t; f < 96 * 32; f += TB) {
                int j = f >> 5, c = f & 31;
                ws[j * XSTR + c] = kv_w[(h * 96 + j) * 256 + kc + c];
            }
            __syncthreads();
            #pragma unroll 2
            for (int c = 0; c < 32; ++c) {
                float wv[12], xv[7];
                #pragma unroll
                for (int jj = 0; jj < 12; ++jj) wv[jj] = ws[(jt * 12 + jj) * XSTR + c];
                #pragma unroll
                for (int k = 0; k < 7; ++k) xv[k] = xs[(nt + 32 * k) * XSTR + c];
                #pragma unroll
                for (int k = 0; k < 7; ++k)
                    #pragma unroll
                    for (int jj = 0; jj < 12; ++jj)
                        acc[k][jj] += xv[k] * wv[jj];
            }
        }
        float iv[12], be[12];
        #pragma unroll
        for (int jj = 0; jj < 12; ++jj) {
            int col = h * 96 + jt * 12 + jj;
            iv[jj] = kv_g[col] * rsqrtf(kv_v[col] + 1e-5f);
            be[jj] = kv_b[col] - kv_m[col] * iv[jj];
        }
        #pragma unroll
        for (int k = 0; k < 7; ++k) {
            int n = nt + 32 * k;
            if (n < 196) {
                #pragma unroll
                for (int jj = 0; jj < 12; ++jj) {
                    int j = jt * 12 + jj;
                    float val = acc[k][jj] * iv[jj] + be[jj];
                    if (j < 32) kbuf[n * KSTR + j] = val;
                    else        vbuf[n * VSTR + (j - 32)] = val;
                }
            }
        }
    }
    __syncthreads();

    // ---------------- Phase 2a: scores = softmax(q k^T * scale + bias) (per wave per row)
    float* scores = un;   // [49][SSTR]
    {
        const int lane = t & 63;
        const int w = t >> 6;   // wave 0..3
        for (int rk = 0; rk < 13; ++rk) {
            int qi = w + 4 * rk;
            if (qi >= 49) break;   // wave-uniform
            const int yq = (qi / 7) * 2, xq2 = (qi % 7) * 2;
            float4 qv[8];
            #pragma unroll
            for (int i = 0; i < 8; ++i)
                qv[i] = *(const float4*)&qbuf[qi * QSTR + 4 * i];
            float lmax = -3.0e38f;
            for (int n = lane; n < 196; n += 64) {
                float s = 0.f;
                #pragma unroll
                for (int i = 0; i < 8; ++i) {
                    float4 kk = *(const float4*)&kbuf[n * KSTR + 4 * i];
                    s += qv[i].x * kk.x + qv[i].y * kk.y + qv[i].z * kk.z + qv[i].w * kk.w;
                }
                int yk = n / 14, xk = n - 14 * (n / 14);
                int r0 = yq >= yk ? yq - yk : yk - yq;
                int r1 = xq2 >= xk ? xq2 - xk : xk - xq2;
                s = s * 0.17677669529663687f + attn_bias[h * 196 + r0 * 14 + r1];
                scores[qi * SSTR + n] = s;
                lmax = fmaxf(lmax, s);
            }
            #pragma unroll
            for (int off = 32; off > 0; off >>= 1)
                lmax = fmaxf(lmax, __shfl_xor(lmax, off, 64));
            float lsum = 0.f;
            for (int n = lane; n < 196; n += 64) {
                float p = __expf(scores[qi * SSTR + n] - lmax);
                scores[qi * SSTR + n] = p;
                lsum += p;
            }
            #pragma unroll
            for (int off = 32; off > 0; off >>= 1)
                lsum += __shfl_xor(lsum, off, 64);
            if (lane == 0) rstat[qi] = 1.f / lsum;
        }
    }
    __syncthreads();

    // ---------------- Phase 2b: out = (p @ v) / rowsum -> attn_out[b][qi][h*64+vd]
    {
        const int vq = (t & 15) * 4;    // float4 of v
        const int qt = t >> 4;          // 0..15; qi = qt + 16*k
        int rowoff[4];
        #pragma unroll
        for (int k = 0; k < 4; ++k) {
            int qi = qt + 16 * k;
            rowoff[k] = (qi < 49 ? qi : 48) * SSTR;   // clamp: garbage masked at store
        }
        float4 acc[4] = {};
        for (int n = 0; n < 196; ++n) {
            const float4 vv = *(const float4*)&vbuf[n * VSTR + vq];
            #pragma unroll
            for (int k = 0; k < 4; ++k) {
                float p = scores[rowoff[k] + n];
                acc[k].x += p * vv.x; acc[k].y += p * vv.y;
                acc[k].z += p * vv.z; acc[k].w += p * vv.w;
            }
        }
        #pragma unroll
        for (int k = 0; k < 4; ++k) {
            int qi = qt + 16 * k;
            if (qi < 49) {
                float r = rstat[qi];
                float4 o;
                o.x = acc[k].x * r; o.y = acc[k].y * r;
                o.z = acc[k].z * r; o.w = acc[k].w * r;
                *(float4*)&attn_out[((b * 49 + qi) * 8 + h) * 64 + vq] = o;
            }
        }
    }
}

// out = linear_norm(hardswish(A), proj_w)  : [12544,512] @ [512,384]^T
__global__ __launch_bounds__(256, 1)
void levit_proj(const float* __restrict__ A,
                const float* __restrict__ pw, const float* __restrict__ pg,
                const float* __restrict__ pb, const float* __restrict__ pm,
                const float* __restrict__ pv,
                float* __restrict__ out)
{
    constexpr int AST = 33, WST = 33;
    __shared__ float As[52 * AST];     // rows >=49 zero
    __shared__ float Ws[384 * WST];
    const int t = threadIdx.x;
    const int b = blockIdx.x;
    const int ot = t & 63;   // o = ot + 64*m
    const int rt = t >> 6;   // r = rt + 4*k
    float acc[13][6] = {};
    for (int kc = 0; kc < 512; kc += 32) {
        __syncthreads();
        for (int f = t; f < 52 * 32; f += 256) {
            int r = f >> 5, c = f & 31;
            float hs = 0.f;
            if (r < 49) {
                float v = A[(b * 49 + r) * 512 + kc + c];
                hs = v * fminf(fmaxf(v + 3.f, 0.f), 6.f) * (1.f / 6.f);
            }
            As[r * AST + c] = hs;
        }
        for (int f = t; f < 384 * 32; f += 256) {
            int o = f >> 5, c = f & 31;
            Ws[o * WST + c] = pw[o * 512 + kc + c];
        }
        __syncthreads();
        #pragma unroll 2
        for (int c = 0; c < 32; ++c) {
            float wv[6], av[13];
            #pragma unroll
            for (int m = 0; m < 6; ++m) wv[m] = Ws[(ot + 64 * m) * WST + c];
            #pragma unroll
            for (int k = 0; k < 13; ++k) av[k] = As[(rt + 4 * k) * AST + c];
            #pragma unroll
            for (int k = 0; k < 13; ++k)
                #pragma unroll
                for (int m = 0; m < 6; ++m)
                    acc[k][m] += av[k] * wv[m];
        }
    }
    #pragma unroll
    for (int m = 0; m < 6; ++m) {
        int o = ot + 64 * m;
        float iv = pg[o] * rsqrtf(pv[o] + 1e-5f);
        float be = pb[o] - pm[o] * iv;
        #pragma unroll
        for (int k = 0; k < 13; ++k) {
            int r = rt + 4 * k;
            if (r < 49) out[(b * 49 + r) * 384 + o] = acc[k][m] * iv + be;
        }
    }
}

extern "C" void kernel_launch(void* const* d_in, const int* in_sizes, int n_in,
                              void* d_out, int out_size, void* d_ws, size_t ws_size,
                              hipStream_t stream) {
    const float* x     = (const float*)d_in[0];
    const float* kv_w  = (const float*)d_in[1];
    const float* kv_g  = (const float*)d_in[2];
    const float* kv_b  = (const float*)d_in[3];
    const float* kv_m  = (const float*)d_in[4];
    const float* kv_v  = (const float*)d_in[5];
    const float* q_w   = (const float*)d_in[6];
    const float* q_g   = (const float*)d_in[7];
    const float* q_b   = (const float*)d_in[8];
    const float* q_m   = (const float*)d_in[9];
    const float* q_v   = (const float*)d_in[10];
    const float* pw    = (const float*)d_in[11];
    const float* pg    = (const float*)d_in[12];
    const float* pb    = (const float*)d_in[13];
    const float* pm    = (const float*)d_in[14];
    const float* pv    = (const float*)d_in[15];
    const float* ab    = (const float*)d_in[16];

    float* attn_out = (float*)d_ws;   // 256*49*512 floats = 25.7 MB

    dim3 g1(256, 8);   // (b, h): b-major so same-b blocks share an XCD
    levit_fused_attn<<<g1, 256, 0, stream>>>(x, kv_w, kv_g, kv_b, kv_m, kv_v,
                                             q_w, q_g, q_b, q_m, q_v, ab, attn_out);
    levit_proj<<<dim3(256), 256, 0, stream>>>(attn_out, pw, pg, pb, pm, pv,
                                              (float*)d_out);
}

// Round 2
// 1144.013 us; speedup vs baseline: 1.5075x; 1.5075x over previous
//
#include <hip/hip_runtime.h>

// B=256, N=196, C=256, H=8, KD=32, VD=64, Q=49, R=14
constexpr int TB = 512;
#define EPS 1e-5f
#define QK_SCALE 0.17677669529663687f

// LDS map (129.7 KB, 1 block/CU, 512 thr = 8 waves/CU):
//   un:    stage xs[224][33] + ws[128][33]  (46464 B)  -- union with scores[49][200] (39200 B)
//   kT:    k transposed [32][200] (+zero pad col 196)  (25616 B)
//   vbuf:  [196][64]                                   (50176 B)
//   qbuf:  [49][33]                                    (6468 B)
__global__ __launch_bounds__(512, 2)
void levit_fused_attn(const float* __restrict__ x,
                      const float* __restrict__ kv_w, const float* __restrict__ kv_g,
                      const float* __restrict__ kv_b, const float* __restrict__ kv_m,
                      const float* __restrict__ kv_v,
                      const float* __restrict__ q_w, const float* __restrict__ q_g,
                      const float* __restrict__ q_b, const float* __restrict__ q_m,
                      const float* __restrict__ q_v,
                      const float* __restrict__ attn_bias,
                      float* __restrict__ attn_out)
{
    __shared__ float un[(224 + 128) * 33];
    __shared__ float kT[32 * 200 + 4];
    __shared__ float vbuf[196 * 64];
    __shared__ float qbuf[49 * 33];
    __shared__ float bias_s[196];
    __shared__ float rstat[52];

    const int t = threadIdx.x;
    const int b = blockIdx.x;
    const int h = blockIdx.y;

    float* xs = un;                 // [224][33], rows >=196 zero
    float* ws = un + 224 * 33;      // [128][33]: rows 0..95 kv_w, 96..127 q_w

    if (t < 196) bias_s[t] = attn_bias[h * 196 + t];
    if (t < 32)  kT[t * 200 + 196] = 0.f;   // zero pad column for masked QK lanes

    // ---------------- Merged GEMM: [196 x 128] = x[196 x 256] @ [kv_w; q_w]^T
    const int jt = t & 15;          // col group: j = jt*8 + jj
    const int nt = t >> 4;          // rows: n = nt + 32k, k<7

    float acc[7][8] = {};
    for (int kc = 0; kc < 256; kc += 32) {
        __syncthreads();
        #pragma unroll
        for (int i = 0; i < 14; ++i) {          // xs: 224*32 / 512
            int f = t + TB * i;
            int n = f >> 5, c = f & 31;
            xs[n * 33 + c] = (n < 196) ? x[(b * 196 + n) * 256 + kc + c] : 0.f;
        }
        #pragma unroll
        for (int i = 0; i < 8; ++i) {           // ws: 128*32 / 512
            int f = t + TB * i;
            int j = f >> 5, c = f & 31;
            ws[j * 33 + c] = (j < 96) ? kv_w[(h * 96 + j) * 256 + kc + c]
                                      : q_w[(h * 32 + j - 96) * 256 + kc + c];
        }
        __syncthreads();
        #pragma unroll 4
        for (int c = 0; c < 32; ++c) {
            float wv[8], xv[7];
            #pragma unroll
            for (int jj = 0; jj < 8; ++jj) wv[jj] = ws[(jt * 8 + jj) * 33 + c];
            #pragma unroll
            for (int k = 0; k < 7; ++k) xv[k] = xs[(nt + 32 * k) * 33 + c];
            #pragma unroll
            for (int k = 0; k < 7; ++k)
                #pragma unroll
                for (int jj = 0; jj < 8; ++jj)
                    acc[k][jj] += xv[k] * wv[jj];
        }
    }
    // epilogue: per-col norm, scatter to kT / vbuf / qbuf
    {
        float iv[8], be[8];
        #pragma unroll
        for (int jj = 0; jj < 8; ++jj) {
            int j = jt * 8 + jj;
            float g, bb, mm, vv;
            if (j < 96) { int col = h * 96 + j;      g = kv_g[col]; bb = kv_b[col]; mm = kv_m[col]; vv = kv_v[col]; }
            else        { int col = h * 32 + j - 96; g = q_g[col];  bb = q_b[col];  mm = q_m[col];  vv = q_v[col]; }
            float ivv = g * rsqrtf(vv + EPS);
            iv[jj] = ivv; be[jj] = bb - mm * ivv;
        }
        #pragma unroll
        for (int k = 0; k < 7; ++k) {
            int n = nt + 32 * k;
            if (n < 196) {
                int a = n / 28, rem = n - 28 * a;
                bool isq = (rem < 14) && !(rem & 1);
                int qi = a * 7 + (rem >> 1);
                #pragma unroll
                for (int jj = 0; jj < 8; ++jj) {
                    int j = jt * 8 + jj;
                    float val = acc[k][jj] * iv[jj] + be[jj];
                    if (j < 32)      kT[j * 200 + n] = val;
                    else if (j < 96) vbuf[n * 64 + (j - 32)] = val;
                    else if (isq)    qbuf[qi * 33 + (j - 96)] = val;
                }
            }
        }
    }
    __syncthreads();

    // ---------------- Phase 2a: scores rows, softmax (8 waves x 7 rows)
    float* scores = un;   // [49][200] -- staging area is dead now
    {
        const int lane = t & 63;
        const int w = t >> 6;
        const int i3 = (lane + 192 < 196) ? lane + 192 : 196;   // clamp to zero pad col
        for (int rk = 0; rk < 7; ++rk) {
            int qi = w + 8 * rk;
            if (qi >= 49) break;          // wave-uniform
            float qv[32];
            #pragma unroll
            for (int d = 0; d < 32; ++d) qv[d] = qbuf[qi * 33 + d];
            float s0 = 0.f, s1 = 0.f, s2 = 0.f, s3 = 0.f;
            #pragma unroll 8
            for (int d = 0; d < 32; ++d) {
                const float* kr = &kT[d * 200];
                float qd = qv[d];
                s0 += qd * kr[lane];
                s1 += qd * kr[lane + 64];
                s2 += qd * kr[lane + 128];
                s3 += qd * kr[i3];
            }
            const int yq = (qi / 7) * 2, xq2 = (qi % 7) * 2;
            float sv[4] = {s0, s1, s2, s3};
            float lmax = -3.0e38f;
            #pragma unroll
            for (int ni = 0; ni < 4; ++ni) {
                int n = lane + 64 * ni;
                if (n < 196) {
                    int yk = n / 14, xk = n - 14 * yk;
                    int r0 = yq >= yk ? yq - yk : yk - yq;
                    int r1 = xq2 >= xk ? xq2 - xk : xk - xq2;
                    sv[ni] = sv[ni] * QK_SCALE + bias_s[r0 * 14 + r1];
                    lmax = fmaxf(lmax, sv[ni]);
                }
            }
            #pragma unroll
            for (int off = 32; off > 0; off >>= 1)
                lmax = fmaxf(lmax, __shfl_xor(lmax, off, 64));
            float lsum = 0.f;
            #pragma unroll
            for (int ni = 0; ni < 4; ++ni) {
                int n = lane + 64 * ni;
                if (n < 196) {
                    float p = __expf(sv[ni] - lmax);
                    scores[qi * 200 + n] = p;
                    lsum += p;
                }
            }
            #pragma unroll
            for (int off = 32; off > 0; off >>= 1)
                lsum += __shfl_xor(lsum, off, 64);
            if (lane == 0) rstat[qi] = 1.f / lsum;
        }
    }
    __syncthreads();

    // ---------------- Phase 2b: out = (p @ v) / rowsum
    {
        const int vq = (t & 15) * 4;      // float4 column of v
        const int qt = t >> 4;            // 0..31; rows qt and qt+32
        const int off0 = qt * 200;
        const int off1 = (qt < 17 ? qt + 32 : 16) * 200;   // dummy valid row when masked
        float4 a0 = {0, 0, 0, 0}, a1 = {0, 0, 0, 0};
        #pragma unroll 2
        for (int n = 0; n < 196; n += 2) {
            float4 v0 = *(const float4*)&vbuf[n * 64 + vq];
            float4 v1 = *(const float4*)&vbuf[(n + 1) * 64 + vq];
            float2 p0 = *(const float2*)&scores[off0 + n];
            float2 p1 = *(const float2*)&scores[off1 + n];
            a0.x += p0.x * v0.x; a0.y += p0.x * v0.y; a0.z += p0.x * v0.z; a0.w += p0.x * v0.w;
            a0.x += p0.y * v1.x; a0.y += p0.y * v1.y; a0.z += p0.y * v1.z; a0.w += p0.y * v1.w;
            a1.x += p1.x * v0.x; a1.y += p1.x * v0.y; a1.z += p1.x * v0.z; a1.w += p1.x * v0.w;
            a1.x += p1.y * v1.x; a1.y += p1.y * v1.y; a1.z += p1.y * v1.z; a1.w += p1.y * v1.w;
        }
        {
            float r = rstat[qt];
            float4 o = {a0.x * r, a0.y * r, a0.z * r, a0.w * r};
            *(float4*)&attn_out[((b * 49 + qt) * 8 + h) * 64 + vq] = o;
        }
        if (qt < 17) {
            float r = rstat[qt + 32];
            float4 o = {a1.x * r, a1.y * r, a1.z * r, a1.w * r};
            *(float4*)&attn_out[((b * 49 + qt + 32) * 8 + h) * 64 + vq] = o;
        }
    }
}

// out = linear_norm(hardswish(A), proj_w) : per block [49 x 512] @ [512 x 384]^T
__global__ __launch_bounds__(512, 2)
void levit_proj(const float* __restrict__ A,
                const float* __restrict__ pw, const float* __restrict__ pg,
                const float* __restrict__ pb, const float* __restrict__ pm,
                const float* __restrict__ pv,
                float* __restrict__ out)
{
    __shared__ float As[56 * 33];     // rows >=49 zero
    __shared__ float Ws[384 * 33];
    const int t = threadIdx.x;
    const int b = blockIdx.x;
    const int ot = t & 63;            // cols o = ot + 64m, m<6
    const int rt = t >> 6;            // rows r = rt + 8k, k<7
    float acc[7][6] = {};
    for (int kc = 0; kc < 512; kc += 32) {
        __syncthreads();
        for (int f = t; f < 56 * 32; f += TB) {
            int r = f >> 5, c = f & 31;
            float hs = 0.f;
            if (r < 49) {
                float v = A[(b * 49 + r) * 512 + kc + c];
                hs = v * fminf(fmaxf(v + 3.f, 0.f), 6.f) * (1.f / 6.f);
            }
            As[r * 33 + c] = hs;
        }
        #pragma unroll
        for (int i = 0; i < 24; ++i) {      // 384*32 / 512
            int f = t + TB * i;
            int o = f >> 5, c = f & 31;
            Ws[o * 33 + c] = pw[o * 512 + kc + c];
        }
        __syncthreads();
        #pragma unroll 4
        for (int c = 0; c < 32; ++c) {
            float wv[6], av[7];
            #pragma unroll
            for (int m = 0; m < 6; ++m) wv[m] = Ws[(ot + 64 * m) * 33 + c];
            #pragma unroll
            for (int k = 0; k < 7; ++k) av[k] = As[(rt + 8 * k) * 33 + c];
            #pragma unroll
            for (int k = 0; k < 7; ++k)
                #pragma unroll
                for (int m = 0; m < 6; ++m)
                    acc[k][m] += av[k] * wv[m];
        }
    }
    #pragma unroll
    for (int m = 0; m < 6; ++m) {
        int o = ot + 64 * m;
        float iv = pg[o] * rsqrtf(pv[o] + EPS);
        float be = pb[o] - pm[o] * iv;
        #pragma unroll
        for (int k = 0; k < 7; ++k) {
            int r = rt + 8 * k;
            if (r < 49) out[(b * 49 + r) * 384 + o] = acc[k][m] * iv + be;
        }
    }
}

extern "C" void kernel_launch(void* const* d_in, const int* in_sizes, int n_in,
                              void* d_out, int out_size, void* d_ws, size_t ws_size,
                              hipStream_t stream) {
    const float* x     = (const float*)d_in[0];
    const float* kv_w  = (const float*)d_in[1];
    const float* kv_g  = (const float*)d_in[2];
    const float* kv_b  = (const float*)d_in[3];
    const float* kv_m  = (const float*)d_in[4];
    const float* kv_v  = (const float*)d_in[5];
    const float* q_w   = (const float*)d_in[6];
    const float* q_g   = (const float*)d_in[7];
    const float* q_b   = (const float*)d_in[8];
    const float* q_m   = (const float*)d_in[9];
    const float* q_v   = (const float*)d_in[10];
    const float* pw    = (const float*)d_in[11];
    const float* pg    = (const float*)d_in[12];
    const float* pb    = (const float*)d_in[13];
    const float* pm    = (const float*)d_in[14];
    const float* pv    = (const float*)d_in[15];
    const float* ab    = (const float*)d_in[16];

    float* attn_out = (float*)d_ws;   // 256*49*512 floats = 25.7 MB

    dim3 g1(256, 8);   // linear id = b + 256h -> all 8 heads of batch b on one XCD
    levit_fused_attn<<<g1, TB, 0, stream>>>(x, kv_w, kv_g, kv_b, kv_m, kv_v,
                                            q_w, q_g, q_b, q_m, q_v, ab, attn_out);
    levit_proj<<<dim3(256), TB, 0, stream>>>(attn_out, pw, pg, pb, pm, pv,
                                             (float*)d_out);
}

// Round 3
// 796.435 us; speedup vs baseline: 2.1653x; 1.4364x over previous
//
#include <hip/hip_runtime.h>

// B=256, N=196, C=256, H=8, KD=32, VD=64, Q=49, R=14
constexpr int TB = 512;
#define EPS 1e-5f
#define QK_SCALE 0.17677669529663687f

// LDS map (~131.4 KB, 1 block/CU, 512 thr = 8 waves):
//   un:   stage xs[224][36] + ws[128][36] (50688 B) -- union with scores[49][200]
//   kT:   k transposed [32][200], cols 196..199 zero (25600 B)
//   vbuf: [196][64] (50176 B)
//   qbuf: [49][36]  (7056 B)
__global__ __launch_bounds__(512, 2)
void levit_fused_attn(const float* __restrict__ x,
                      const float* __restrict__ kv_w, const float* __restrict__ kv_g,
                      const float* __restrict__ kv_b, const float* __restrict__ kv_m,
                      const float* __restrict__ kv_v,
                      const float* __restrict__ q_w, const float* __restrict__ q_g,
                      const float* __restrict__ q_b, const float* __restrict__ q_m,
                      const float* __restrict__ q_v,
                      const float* __restrict__ attn_bias,
                      float* __restrict__ attn_out)
{
    __shared__ float un[(224 + 128) * 36];
    __shared__ float kT[32 * 200];
    __shared__ float vbuf[196 * 64];
    __shared__ float qbuf[49 * 36];
    __shared__ float bias_s[196];
    __shared__ float rstat[52];

    const int t = threadIdx.x;
    const int b = blockIdx.x;
    const int h = blockIdx.y;

    float* xs = un;                 // [224][36], rows >=196 zero
    float* ws = un + 224 * 36;      // [128][36]: rows 0..95 kv_w, 96..127 q_w

    if (t < 196) bias_s[t] = attn_bias[h * 196 + t];
    if (t < 32)  *(float4*)&kT[t * 200 + 196] = float4{0.f, 0.f, 0.f, 0.f};

    // ---------------- Merged GEMM: [196 x 128] = x[196 x 256] @ [kv_w; q_w]^T
    // col mapping j = jt + 16*jj  (ws read stride 36 across lanes -> 2-way max, free)
    const int jt = t & 15;
    const int nt = t >> 4;          // rows n = nt + 32k, k<7

    float acc[7][8] = {};
    for (int kc = 0; kc < 256; kc += 32) {
        __syncthreads();
        #pragma unroll
        for (int i = 0; i < 4; ++i) {           // xs: 224 rows x 8 float4
            int f = t + TB * i;
            if (f < 224 * 8) {
                int n = f >> 3, c4 = (f & 7) * 4;
                float4 v = {0.f, 0.f, 0.f, 0.f};
                if (n < 196) v = *(const float4*)&x[(b * 196 + n) * 256 + kc + c4];
                *(float4*)&xs[n * 36 + c4] = v;
            }
        }
        #pragma unroll
        for (int i = 0; i < 2; ++i) {           // ws: 128 rows x 8 float4
            int f = t + TB * i;
            int j = f >> 3, c4 = (f & 7) * 4;
            const float* src = (j < 96) ? &kv_w[(h * 96 + j) * 256 + kc + c4]
                                        : &q_w[(h * 32 + j - 96) * 256 + kc + c4];
            *(float4*)&ws[j * 36 + c4] = *(const float4*)src;
        }
        __syncthreads();
        #pragma unroll 2
        for (int c4 = 0; c4 < 32; c4 += 4) {
            float4 xv[7], wv[8];
            #pragma unroll
            for (int k = 0; k < 7; ++k)  xv[k] = *(const float4*)&xs[(nt + 32 * k) * 36 + c4];
            #pragma unroll
            for (int jj = 0; jj < 8; ++jj) wv[jj] = *(const float4*)&ws[(jt + 16 * jj) * 36 + c4];
            #pragma unroll
            for (int k = 0; k < 7; ++k)
                #pragma unroll
                for (int jj = 0; jj < 8; ++jj)
                    acc[k][jj] += xv[k].x * wv[jj].x + xv[k].y * wv[jj].y
                                + xv[k].z * wv[jj].z + xv[k].w * wv[jj].w;
        }
    }
    // epilogue: per-col norm, scatter to kT / vbuf / qbuf
    {
        float iv[8], be[8];
        #pragma unroll
        for (int jj = 0; jj < 8; ++jj) {
            int j = jt + 16 * jj;
            float g, bb, mm, vv;
            if (j < 96) { int col = h * 96 + j;      g = kv_g[col]; bb = kv_b[col]; mm = kv_m[col]; vv = kv_v[col]; }
            else        { int col = h * 32 + j - 96; g = q_g[col];  bb = q_b[col];  mm = q_m[col];  vv = q_v[col]; }
            float ivv = g * rsqrtf(vv + EPS);
            iv[jj] = ivv; be[jj] = bb - mm * ivv;
        }
        #pragma unroll
        for (int k = 0; k < 7; ++k) {
            int n = nt + 32 * k;
            if (n < 196) {
                int a = n / 28, rem = n - 28 * a;
                bool isq = (rem < 14) && !(rem & 1);
                int qi = a * 7 + (rem >> 1);
                #pragma unroll
                for (int jj = 0; jj < 8; ++jj) {
                    int j = jt + 16 * jj;
                    float val = acc[k][jj] * iv[jj] + be[jj];
                    if (j < 32)      kT[j * 200 + n] = val;
                    else if (j < 96) vbuf[n * 64 + (j - 32)] = val;
                    else if (isq)    qbuf[qi * 36 + (j - 96)] = val;
                }
            }
        }
    }
    __syncthreads();

    // ---------------- Phase 2a: scores + softmax (wave per row, lane per 4 n)
    float* scores = un;
    {
        const int lane = t & 63;
        const int w = t >> 6;
        const int n0 = 4 * lane;
        const int n0c = (n0 <= 196) ? n0 : 196;   // clamp into zero pad
        const bool act = (n0 < 196);              // lanes 0..48 (196 = 49*4 exactly)
        for (int rk = 0; rk < 7; ++rk) {
            int qi = w + 8 * rk;
            if (qi >= 49) break;                  // wave-uniform
            float4 qv[8];
            #pragma unroll
            for (int i = 0; i < 8; ++i)
                qv[i] = *(const float4*)&qbuf[qi * 36 + 4 * i];
            float4 s4 = {0.f, 0.f, 0.f, 0.f};
            #define QK_STEP(qc, d) { \
                float4 kk = *(const float4*)&kT[(d) * 200 + n0c]; \
                s4.x += (qc) * kk.x; s4.y += (qc) * kk.y; \
                s4.z += (qc) * kk.z; s4.w += (qc) * kk.w; }
            #pragma unroll
            for (int i = 0; i < 8; ++i) {
                QK_STEP(qv[i].x, 4 * i + 0)
                QK_STEP(qv[i].y, 4 * i + 1)
                QK_STEP(qv[i].z, 4 * i + 2)
                QK_STEP(qv[i].w, 4 * i + 3)
            }
            #undef QK_STEP
            const int yq = (qi / 7) * 2, xq2 = (qi % 7) * 2;
            float sv[4] = {s4.x, s4.y, s4.z, s4.w};
            float lmax = -3.0e38f;
            if (act) {
                #pragma unroll
                for (int ni = 0; ni < 4; ++ni) {
                    int n = n0 + ni;
                    int yk = n / 14, xk = n - 14 * yk;
                    int r0 = yq >= yk ? yq - yk : yk - yq;
                    int r1 = xq2 >= xk ? xq2 - xk : xk - xq2;
                    sv[ni] = sv[ni] * QK_SCALE + bias_s[r0 * 14 + r1];
                    lmax = fmaxf(lmax, sv[ni]);
                }
            }
            #pragma unroll
            for (int off = 32; off > 0; off >>= 1)
                lmax = fmaxf(lmax, __shfl_xor(lmax, off, 64));
            float lsum = 0.f;
            float4 p4 = {0.f, 0.f, 0.f, 0.f};
            if (act) {
                p4.x = __expf(sv[0] - lmax); p4.y = __expf(sv[1] - lmax);
                p4.z = __expf(sv[2] - lmax); p4.w = __expf(sv[3] - lmax);
                lsum = p4.x + p4.y + p4.z + p4.w;
                *(float4*)&scores[qi * 200 + n0] = p4;
            }
            #pragma unroll
            for (int off = 32; off > 0; off >>= 1)
                lsum += __shfl_xor(lsum, off, 64);
            if (lane == 0) rstat[qi] = 1.f / lsum;
        }
    }
    __syncthreads();

    // ---------------- Phase 2b: out = (p @ v) / rowsum
    {
        const int vq = (t & 15) * 4;      // float4 column of v
        const int qt = t >> 4;            // 0..31; rows qt and qt+32
        const int off0 = qt * 200;
        const int off1 = (qt < 17 ? qt + 32 : 16) * 200;
        float4 a0 = {0, 0, 0, 0}, a1 = {0, 0, 0, 0};
        #pragma unroll 2
        for (int n = 0; n < 196; n += 2) {
            float4 v0 = *(const float4*)&vbuf[n * 64 + vq];
            float4 v1 = *(const float4*)&vbuf[(n + 1) * 64 + vq];
            float2 p0 = *(const float2*)&scores[off0 + n];
            float2 p1 = *(const float2*)&scores[off1 + n];
            a0.x += p0.x * v0.x; a0.y += p0.x * v0.y; a0.z += p0.x * v0.z; a0.w += p0.x * v0.w;
            a0.x += p0.y * v1.x; a0.y += p0.y * v1.y; a0.z += p0.y * v1.z; a0.w += p0.y * v1.w;
            a1.x += p1.x * v0.x; a1.y += p1.x * v0.y; a1.z += p1.x * v0.z; a1.w += p1.x * v0.w;
            a1.x += p1.y * v1.x; a1.y += p1.y * v1.y; a1.z += p1.y * v1.z; a1.w += p1.y * v1.w;
        }
        {
            float r = rstat[qt];
            float4 o = {a0.x * r, a0.y * r, a0.z * r, a0.w * r};
            *(float4*)&attn_out[((b * 49 + qt) * 8 + h) * 64 + vq] = o;
        }
        if (qt < 17) {
            float r = rstat[qt + 32];
            float4 o = {a1.x * r, a1.y * r, a1.z * r, a1.w * r};
            *(float4*)&attn_out[((b * 49 + qt + 32) * 8 + h) * 64 + vq] = o;
        }
    }
}

// out = linear_norm(hardswish(A), proj_w) : per block [49 x 512] @ [512 x 384]^T
__global__ __launch_bounds__(512, 2)
void levit_proj(const float* __restrict__ A,
                const float* __restrict__ pw, const float* __restrict__ pg,
                const float* __restrict__ pb, const float* __restrict__ pm,
                const float* __restrict__ pv,
                float* __restrict__ out)
{
    __shared__ float As[56 * 36];     // rows >=49 zero
    __shared__ float Ws[384 * 36];
    const int t = threadIdx.x;
    const int b = blockIdx.x;
    const int ot = t & 63;            // cols o = ot + 64m, m<6
    const int rt = t >> 6;            // rows r = rt + 8k, k<7 (wave-uniform -> broadcast reads)
    float acc[7][6] = {};
    for (int kc = 0; kc < 512; kc += 32) {
        __syncthreads();
        {                                       // As: 56 rows x 8 float4 = 448
            int f = t;
            if (f < 56 * 8) {
                int r = f >> 3, c4 = (f & 7) * 4;
                float4 hv = {0.f, 0.f, 0.f, 0.f};
                if (r < 49) {
                    float4 v = *(const float4*)&A[(b * 49 + r) * 512 + kc + c4];
                    hv.x = v.x * fminf(fmaxf(v.x + 3.f, 0.f), 6.f) * (1.f / 6.f);
                    hv.y = v.y * fminf(fmaxf(v.y + 3.f, 0.f), 6.f) * (1.f / 6.f);
                    hv.z = v.z * fminf(fmaxf(v.z + 3.f, 0.f), 6.f) * (1.f / 6.f);
                    hv.w = v.w * fminf(fmaxf(v.w + 3.f, 0.f), 6.f) * (1.f / 6.f);
                }
                *(float4*)&As[r * 36 + c4] = hv;
            }
        }
        #pragma unroll
        for (int i = 0; i < 6; ++i) {           // Ws: 384 rows x 8 float4 = 3072
            int f = t + TB * i;
            int o = f >> 3, c4 = (f & 7) * 4;
            *(float4*)&Ws[o * 36 + c4] = *(const float4*)&pw[o * 512 + kc + c4];
        }
        __syncthreads();
        #pragma unroll 2
        for (int c4 = 0; c4 < 32; c4 += 4) {
            float4 av[7], wv[6];
            #pragma unroll
            for (int k = 0; k < 7; ++k) av[k] = *(const float4*)&As[(rt + 8 * k) * 36 + c4];
            #pragma unroll
            for (int m = 0; m < 6; ++m) wv[m] = *(const float4*)&Ws[(ot + 64 * m) * 36 + c4];
            #pragma unroll
            for (int k = 0; k < 7; ++k)
                #pragma unroll
                for (int m = 0; m < 6; ++m)
                    acc[k][m] += av[k].x * wv[m].x + av[k].y * wv[m].y
                               + av[k].z * wv[m].z + av[k].w * wv[m].w;
        }
    }
    #pragma unroll
    for (int m = 0; m < 6; ++m) {
        int o = ot + 64 * m;
        float iv = pg[o] * rsqrtf(pv[o] + EPS);
        float be = pb[o] - pm[o] * iv;
        #pragma unroll
        for (int k = 0; k < 7; ++k) {
            int r = rt + 8 * k;
            if (r < 49) out[(b * 49 + r) * 384 + o] = acc[k][m] * iv + be;
        }
    }
}

extern "C" void kernel_launch(void* const* d_in, const int* in_sizes, int n_in,
                              void* d_out, int out_size, void* d_ws, size_t ws_size,
                              hipStream_t stream) {
    const float* x     = (const float*)d_in[0];
    const float* kv_w  = (const float*)d_in[1];
    const float* kv_g  = (const float*)d_in[2];
    const float* kv_b  = (const float*)d_in[3];
    const float* kv_m  = (const float*)d_in[4];
    const float* kv_v  = (const float*)d_in[5];
    const float* q_w   = (const float*)d_in[6];
    const float* q_g   = (const float*)d_in[7];
    const float* q_b   = (const float*)d_in[8];
    const float* q_m   = (const float*)d_in[9];
    const float* q_v   = (const float*)d_in[10];
    const float* pw    = (const float*)d_in[11];
    const float* pg    = (const float*)d_in[12];
    const float* pb    = (const float*)d_in[13];
    const float* pm    = (const float*)d_in[14];
    const float* pv    = (const float*)d_in[15];
    const float* ab    = (const float*)d_in[16];

    float* attn_out = (float*)d_ws;   // 256*49*512 floats = 25.7 MB

    dim3 g1(256, 8);   // linear id = b + 256h -> all 8 heads of batch b on one XCD
    levit_fused_attn<<<g1, TB, 0, stream>>>(x, kv_w, kv_g, kv_b, kv_m, kv_v,
                                            q_w, q_g, q_b, q_m, q_v, ab, attn_out);
    levit_proj<<<dim3(256), TB, 0, stream>>>(attn_out, pw, pg, pb, pm, pv,
                                             (float*)d_out);
}

// Round 4
// 471.084 us; speedup vs baseline: 3.6608x; 1.6906x over previous
//
#include <hip/hip_runtime.h>

// B=256, N=196, C=256, H=8, KD=32, VD=64, Q=49, R=14
constexpr int TB = 512;
#define EPS 1e-5f
#define QK_SCALE 0.17677669529663687f

typedef __attribute__((ext_vector_type(8))) short bf16x8;   // 8 bf16 in 4 VGPRs
typedef __attribute__((ext_vector_type(4))) float f32x4;

__device__ inline unsigned short bf16_rne(float f) {
    unsigned int u = __float_as_uint(f);
    u = u + 0x7FFFu + ((u >> 16) & 1u);
    return (unsigned short)(u >> 16);
}
__device__ inline float bf16_f(unsigned short s) {
    return __uint_as_float(((unsigned int)s) << 16);
}
// split v = hi + lo (each bf16); dropped lo*lo term ~2^-18 rel
__device__ inline void split4(float4 v, ushort4& hi, ushort4& lo) {
    hi.x = bf16_rne(v.x); hi.y = bf16_rne(v.y); hi.z = bf16_rne(v.z); hi.w = bf16_rne(v.w);
    lo.x = bf16_rne(v.x - bf16_f(hi.x));
    lo.y = bf16_rne(v.y - bf16_f(hi.y));
    lo.z = bf16_rne(v.z - bf16_f(hi.z));
    lo.w = bf16_rne(v.w - bf16_f(hi.w));
}

// LDS (~134.4 KB): stage xhi/xlo[208][40] + whi/wlo[128][40] bf16 (53760 B,
// union w/ scores[49][200] f32) | kT[32][200] f32 | vbuf[196][64] | qbuf[49][36]
__global__ __launch_bounds__(512, 2)
void levit_fused_attn(const float* __restrict__ x,
                      const float* __restrict__ kv_w, const float* __restrict__ kv_g,
                      const float* __restrict__ kv_b, const float* __restrict__ kv_m,
                      const float* __restrict__ kv_v,
                      const float* __restrict__ q_w, const float* __restrict__ q_g,
                      const float* __restrict__ q_b, const float* __restrict__ q_m,
                      const float* __restrict__ q_v,
                      const float* __restrict__ attn_bias,
                      float* __restrict__ attn_out)
{
    __shared__ __align__(16) float s_stage_f[13440];   // 53760 B
    __shared__ float kT[32 * 200];
    __shared__ float vbuf[196 * 64];
    __shared__ float qbuf[49 * 36];
    __shared__ float bias_s[196];
    __shared__ float rstat[52];

    unsigned short* s_xhi = (unsigned short*)s_stage_f;          // [208][40]
    unsigned short* s_xlo = s_xhi + 208 * 40;
    unsigned short* s_whi = s_xhi + 416 * 40;                    // [128][40]
    unsigned short* s_wlo = s_xhi + 544 * 40;
    float* scores = s_stage_f;                                   // [49][200] (after GEMM)

    const int t = threadIdx.x;
    const int b = blockIdx.x;
    const int hh = blockIdx.y;

    const int l = t & 63;
    const int w = t >> 6;
    const int wr = w & 1;            // row-tile parity: rt = wr + 2*rti
    const int wc = w >> 1;           // col-tiles 2wc, 2wc+1
    const int lrow = l & 15;
    const int kg = (l >> 4) * 8;     // k offset within 32-chunk
    const int g4 = (l >> 4) * 4;     // C-layout row group
    const int nrt = 7 - wr;          // 7 or 6 row-tiles

    if (t < 196) bias_s[t] = attn_bias[hh * 196 + t];
    if (t < 32)  *(float4*)&kT[t * 200 + 196] = float4{0.f, 0.f, 0.f, 0.f};

    // ---------------- Merged GEMM (MFMA): [208 x 128] = x @ [kv_w; q_w]^T
    f32x4 acc[7][2];
    #pragma unroll
    for (int i = 0; i < 7; ++i) { acc[i][0] = (f32x4){0,0,0,0}; acc[i][1] = (f32x4){0,0,0,0}; }

    for (int kc = 0; kc < 256; kc += 32) {
        __syncthreads();
        #pragma unroll
        for (int i = 0; i < 4; ++i) {            // x: 208 rows x 8 float4 = 1664
            int f = t + TB * i;
            if (f < 208 * 8) {
                int n = f >> 3, c4 = (f & 7) * 4;
                float4 v = {0.f, 0.f, 0.f, 0.f};
                if (n < 196) v = *(const float4*)&x[(b * 196 + n) * 256 + kc + c4];
                ushort4 vh, vl; split4(v, vh, vl);
                *(ushort4*)&s_xhi[n * 40 + c4] = vh;
                *(ushort4*)&s_xlo[n * 40 + c4] = vl;
            }
        }
        #pragma unroll
        for (int i = 0; i < 2; ++i) {            // w: 128 rows x 8 float4 = 1024
            int f = t + TB * i;
            int j = f >> 3, c4 = (f & 7) * 4;
            const float* src = (j < 96) ? &kv_w[(hh * 96 + j) * 256 + kc + c4]
                                        : &q_w[(hh * 32 + j - 96) * 256 + kc + c4];
            float4 v = *(const float4*)src;
            ushort4 vh, vl; split4(v, vh, vl);
            *(ushort4*)&s_whi[j * 40 + c4] = vh;
            *(ushort4*)&s_wlo[j * 40 + c4] = vl;
        }
        __syncthreads();

        bf16x8 bh0 = *(const bf16x8*)&s_whi[(32 * wc + lrow) * 40 + kg];
        bf16x8 bl0 = *(const bf16x8*)&s_wlo[(32 * wc + lrow) * 40 + kg];
        bf16x8 bh1 = *(const bf16x8*)&s_whi[(32 * wc + 16 + lrow) * 40 + kg];
        bf16x8 bl1 = *(const bf16x8*)&s_wlo[(32 * wc + 16 + lrow) * 40 + kg];
        #pragma unroll
        for (int rti = 0; rti < 7; ++rti) {
            if (rti < nrt) {                      // wave-uniform (only rti=6 conditional)
                int arow = 16 * (wr + 2 * rti) + lrow;
                bf16x8 ah = *(const bf16x8*)&s_xhi[arow * 40 + kg];
                bf16x8 al = *(const bf16x8*)&s_xlo[arow * 40 + kg];
                acc[rti][0] = __builtin_amdgcn_mfma_f32_16x16x32_bf16(ah, bh0, acc[rti][0], 0, 0, 0);
                acc[rti][0] = __builtin_amdgcn_mfma_f32_16x16x32_bf16(ah, bl0, acc[rti][0], 0, 0, 0);
                acc[rti][0] = __builtin_amdgcn_mfma_f32_16x16x32_bf16(al, bh0, acc[rti][0], 0, 0, 0);
                acc[rti][1] = __builtin_amdgcn_mfma_f32_16x16x32_bf16(ah, bh1, acc[rti][1], 0, 0, 0);
                acc[rti][1] = __builtin_amdgcn_mfma_f32_16x16x32_bf16(ah, bl1, acc[rti][1], 0, 0, 0);
                acc[rti][1] = __builtin_amdgcn_mfma_f32_16x16x32_bf16(al, bh1, acc[rti][1], 0, 0, 0);
            }
        }
    }

    // epilogue: C-layout row = 16rt + g4 + reg, col = 16ctg + lrow
    #pragma unroll
    for (int ct = 0; ct < 2; ++ct) {
        int ctg = 2 * wc + ct;
        int j = 16 * ctg + lrow;                 // 0..127
        float gg, bb, mm, vv;
        if (ctg < 6) { int col = hh * 96 + j;        gg = kv_g[col]; bb = kv_b[col]; mm = kv_m[col]; vv = kv_v[col]; }
        else         { int col = hh * 32 + (j - 96); gg = q_g[col];  bb = q_b[col];  mm = q_m[col];  vv = q_v[col]; }
        float ivv = gg * rsqrtf(vv + EPS);
        float bee = bb - mm * ivv;
        #pragma unroll
        for (int rti = 0; rti < 7; ++rti) {
            if (rti < nrt) {
                int rt = wr + 2 * rti;
                #pragma unroll
                for (int reg = 0; reg < 4; ++reg) {
                    int n = 16 * rt + g4 + reg;
                    if (n < 196) {
                        float val = acc[rti][ct][reg] * ivv + bee;
                        if (ctg < 2)      kT[j * 200 + n] = val;
                        else if (ctg < 6) vbuf[n * 64 + (j - 32)] = val;
                        else {
                            int a = n / 28, rem = n - 28 * a;
                            if (rem < 14 && !(rem & 1))
                                qbuf[(a * 7 + (rem >> 1)) * 36 + (j - 96)] = val;
                        }
                    }
                }
            }
        }
    }
    __syncthreads();

    // ---------------- Phase 2a: scores + softmax (wave per row, lane per 4 n)
    {
        const int lane = l;
        const int n0 = 4 * lane;
        const int n0c = (n0 <= 196) ? n0 : 196;
        const bool act = (n0 < 196);
        for (int rk = 0; rk < 7; ++rk) {
            int qi = w + 8 * rk;
            if (qi >= 49) break;                  // wave-uniform
            float4 qv[8];
            #pragma unroll
            for (int i = 0; i < 8; ++i)
                qv[i] = *(const float4*)&qbuf[qi * 36 + 4 * i];
            float4 s4 = {0.f, 0.f, 0.f, 0.f};
            #define QK_STEP(qc, d) { \
                float4 kk = *(const float4*)&kT[(d) * 200 + n0c]; \
                s4.x += (qc) * kk.x; s4.y += (qc) * kk.y; \
                s4.z += (qc) * kk.z; s4.w += (qc) * kk.w; }
            #pragma unroll
            for (int i = 0; i < 8; ++i) {
                QK_STEP(qv[i].x, 4 * i + 0)
                QK_STEP(qv[i].y, 4 * i + 1)
                QK_STEP(qv[i].z, 4 * i + 2)
                QK_STEP(qv[i].w, 4 * i + 3)
            }
            #undef QK_STEP
            const int yq = (qi / 7) * 2, xq2 = (qi % 7) * 2;
            float sv[4] = {s4.x, s4.y, s4.z, s4.w};
            float lmax = -3.0e38f;
            if (act) {
                #pragma unroll
                for (int ni = 0; ni < 4; ++ni) {
                    int n = n0 + ni;
                    int yk = n / 14, xk = n - 14 * yk;
                    int r0 = yq >= yk ? yq - yk : yk - yq;
                    int r1 = xq2 >= xk ? xq2 - xk : xk - xq2;
                    sv[ni] = sv[ni] * QK_SCALE + bias_s[r0 * 14 + r1];
                    lmax = fmaxf(lmax, sv[ni]);
                }
            }
            #pragma unroll
            for (int off = 32; off > 0; off >>= 1)
                lmax = fmaxf(lmax, __shfl_xor(lmax, off, 64));
            float lsum = 0.f;
            float4 p4;
            if (act) {
                p4.x = __expf(sv[0] - lmax); p4.y = __expf(sv[1] - lmax);
                p4.z = __expf(sv[2] - lmax); p4.w = __expf(sv[3] - lmax);
                lsum = p4.x + p4.y + p4.z + p4.w;
                *(float4*)&scores[qi * 200 + n0] = p4;
            }
            #pragma unroll
            for (int off = 32; off > 0; off >>= 1)
                lsum += __shfl_xor(lsum, off, 64);
            if (lane == 0) rstat[qi] = 1.f / lsum;
        }
    }
    __syncthreads();

    // ---------------- Phase 2b: out = (p @ v) / rowsum
    {
        const int vq = (t & 15) * 4;
        const int qt = t >> 4;            // 0..31; rows qt and qt+32
        const int off0 = qt * 200;
        const int off1 = (qt < 17 ? qt + 32 : 16) * 200;
        float4 a0 = {0, 0, 0, 0}, a1 = {0, 0, 0, 0};
        #pragma unroll 2
        for (int n = 0; n < 196; n += 2) {
            float4 v0 = *(const float4*)&vbuf[n * 64 + vq];
            float4 v1 = *(const float4*)&vbuf[(n + 1) * 64 + vq];
            float2 p0 = *(const float2*)&scores[off0 + n];
            float2 p1 = *(const float2*)&scores[off1 + n];
            a0.x += p0.x * v0.x; a0.y += p0.x * v0.y; a0.z += p0.x * v0.z; a0.w += p0.x * v0.w;
            a0.x += p0.y * v1.x; a0.y += p0.y * v1.y; a0.z += p0.y * v1.z; a0.w += p0.y * v1.w;
            a1.x += p1.x * v0.x; a1.y += p1.x * v0.y; a1.z += p1.x * v0.z; a1.w += p1.x * v0.w;
            a1.x += p1.y * v1.x; a1.y += p1.y * v1.y; a1.z += p1.y * v1.z; a1.w += p1.y * v1.w;
        }
        {
            float r = rstat[qt];
            float4 o = {a0.x * r, a0.y * r, a0.z * r, a0.w * r};
            *(float4*)&attn_out[((b * 49 + qt) * 8 + hh) * 64 + vq] = o;
        }
        if (qt < 17) {
            float r = rstat[qt + 32];
            float4 o = {a1.x * r, a1.y * r, a1.z * r, a1.w * r};
            *(float4*)&attn_out[((b * 49 + qt + 32) * 8 + hh) * 64 + vq] = o;
        }
    }
}

// out = linear_norm(hardswish(A), proj_w) : per block [49 x 512] @ [512 x 384]^T, MFMA
__global__ __launch_bounds__(512, 2)
void levit_proj(const float* __restrict__ A,
                const float* __restrict__ pw, const float* __restrict__ pg,
                const float* __restrict__ pb, const float* __restrict__ pm,
                const float* __restrict__ pv,
                float* __restrict__ out)
{
    __shared__ __align__(16) float s_mem[17920];   // 71680 B
    unsigned short* s_ahi = (unsigned short*)s_mem;        // [64][40]
    unsigned short* s_alo = s_ahi + 64 * 40;
    unsigned short* s_whi = s_ahi + 128 * 40;              // [384][40]
    unsigned short* s_wlo = s_ahi + 512 * 40;

    const int t = threadIdx.x;
    const int b = blockIdx.x;
    const int l = t & 63;
    const int w = t >> 6;
    const int wr = w & 1;            // row-tiles wr, wr+2
    const int wc = w >> 1;           // col-tiles 6wc .. 6wc+5
    const int lrow = l & 15;
    const int kg = (l >> 4) * 8;
    const int g4 = (l >> 4) * 4;

    f32x4 acc[2][6];
    #pragma unroll
    for (int i = 0; i < 2; ++i)
        #pragma unroll
        for (int j = 0; j < 6; ++j) acc[i][j] = (f32x4){0,0,0,0};

    for (int kc = 0; kc < 512; kc += 32) {
        __syncthreads();
        {                                         // A: 64 rows x 8 f4 = 512
            int r = t >> 3, c4 = (t & 7) * 4;
            float4 hv = {0.f, 0.f, 0.f, 0.f};
            if (r < 49) {
                float4 v = *(const float4*)&A[(b * 49 + r) * 512 + kc + c4];
                hv.x = v.x * fminf(fmaxf(v.x + 3.f, 0.f), 6.f) * (1.f / 6.f);
                hv.y = v.y * fminf(fmaxf(v.y + 3.f, 0.f), 6.f) * (1.f / 6.f);
                hv.z = v.z * fminf(fmaxf(v.z + 3.f, 0.f), 6.f) * (1.f / 6.f);
                hv.w = v.w * fminf(fmaxf(v.w + 3.f, 0.f), 6.f) * (1.f / 6.f);
            }
            ushort4 vh, vl; split4(hv, vh, vl);
            *(ushort4*)&s_ahi[r * 40 + c4] = vh;
            *(ushort4*)&s_alo[r * 40 + c4] = vl;
        }
        #pragma unroll
        for (int i = 0; i < 6; ++i) {             // W: 384 rows x 8 f4 = 3072
            int f = t + TB * i;
            int j = f >> 3, c4 = (f & 7) * 4;
            float4 v = *(const float4*)&pw[j * 512 + kc + c4];
            ushort4 vh, vl; split4(v, vh, vl);
            *(ushort4*)&s_whi[j * 40 + c4] = vh;
            *(ushort4*)&s_wlo[j * 40 + c4] = vl;
        }
        __syncthreads();

        bf16x8 ah[2], al[2];
        #pragma unroll
        for (int r2 = 0; r2 < 2; ++r2) {
            int arow = 16 * (wr + 2 * r2) + lrow;
            ah[r2] = *(const bf16x8*)&s_ahi[arow * 40 + kg];
            al[r2] = *(const bf16x8*)&s_alo[arow * 40 + kg];
        }
        #pragma unroll
        for (int ct = 0; ct < 6; ++ct) {
            int jrow = 16 * (6 * wc + ct) + lrow;
            bf16x8 bh = *(const bf16x8*)&s_whi[jrow * 40 + kg];
            bf16x8 bl = *(const bf16x8*)&s_wlo[jrow * 40 + kg];
            #pragma unroll
            for (int r2 = 0; r2 < 2; ++r2) {
                acc[r2][ct] = __builtin_amdgcn_mfma_f32_16x16x32_bf16(ah[r2], bh, acc[r2][ct], 0, 0, 0);
                acc[r2][ct] = __builtin_amdgcn_mfma_f32_16x16x32_bf16(ah[r2], bl, acc[r2][ct], 0, 0, 0);
                acc[r2][ct] = __builtin_amdgcn_mfma_f32_16x16x32_bf16(al[r2], bh, acc[r2][ct], 0, 0, 0);
            }
        }
    }

    #pragma unroll
    for (int ct = 0; ct < 6; ++ct) {
        int o = 16 * (6 * wc + ct) + lrow;
        float ivv = pg[o] * rsqrtf(pv[o] + EPS);
        float bee = pb[o] - pm[o] * ivv;
        #pragma unroll
        for (int r2 = 0; r2 < 2; ++r2) {
            #pragma unroll
            for (int reg = 0; reg < 4; ++reg) {
                int r = 16 * (wr + 2 * r2) + g4 + reg;
                if (r < 49) out[(b * 49 + r) * 384 + o] = acc[r2][ct][reg] * ivv + bee;
            }
        }
    }
}

extern "C" void kernel_launch(void* const* d_in, const int* in_sizes, int n_in,
                              void* d_out, int out_size, void* d_ws, size_t ws_size,
                              hipStream_t stream) {
    const float* x     = (const float*)d_in[0];
    const float* kv_w  = (const float*)d_in[1];
    const float* kv_g  = (const float*)d_in[2];
    const float* kv_b  = (const float*)d_in[3];
    const float* kv_m  = (const float*)d_in[4];
    const float* kv_v  = (const float*)d_in[5];
    const float* q_w   = (const float*)d_in[6];
    const float* q_g   = (const float*)d_in[7];
    const float* q_b   = (const float*)d_in[8];
    const float* q_m   = (const float*)d_in[9];
    const float* q_v   = (const float*)d_in[10];
    const float* pw    = (const float*)d_in[11];
    const float* pg    = (const float*)d_in[12];
    const float* pb    = (const float*)d_in[13];
    const float* pm    = (const float*)d_in[14];
    const float* pv    = (const float*)d_in[15];
    const float* ab    = (const float*)d_in[16];

    float* attn_out = (float*)d_ws;   // 256*49*512 floats = 25.7 MB

    dim3 g1(256, 8);
    levit_fused_attn<<<g1, TB, 0, stream>>>(x, kv_w, kv_g, kv_b, kv_m, kv_v,
                                            q_w, q_g, q_b, q_m, q_v, ab, attn_out);
    levit_proj<<<dim3(256), TB, 0, stream>>>(attn_out, pw, pg, pb, pm, pv,
                                             (float*)d_out);
}

// Round 5
// 422.109 us; speedup vs baseline: 4.0856x; 1.1160x over previous
//
#include <hip/hip_runtime.h>

// B=256, N=196, C=256, H=8, KD=32, VD=64, Q=49, R=14
constexpr int TB = 512;
#define EPS 1e-5f
#define QK_SCALE 0.17677669529663687f

typedef __attribute__((ext_vector_type(8))) short bf16x8;   // 8 bf16 in 4 VGPRs
typedef __attribute__((ext_vector_type(4))) float f32x4;

__device__ inline unsigned short bf16_rne(float f) {
    unsigned int u = __float_as_uint(f);
    u = u + 0x7FFFu + ((u >> 16) & 1u);
    return (unsigned short)(u >> 16);
}
__device__ inline float bf16_f(unsigned short s) {
    return __uint_as_float(((unsigned int)s) << 16);
}
__device__ inline void split4(float4 v, ushort4& hi, ushort4& lo) {
    hi.x = bf16_rne(v.x); hi.y = bf16_rne(v.y); hi.z = bf16_rne(v.z); hi.w = bf16_rne(v.w);
    lo.x = bf16_rne(v.x - bf16_f(hi.x));
    lo.y = bf16_rne(v.y - bf16_f(hi.y));
    lo.z = bf16_rne(v.z - bf16_f(hi.z));
    lo.w = bf16_rne(v.w - bf16_f(hi.w));
}
__device__ inline void split1(float v, unsigned short& hi, unsigned short& lo) {
    hi = bf16_rne(v); lo = bf16_rne(v - bf16_f(hi));
}

#define MFMA16(a, b, c) __builtin_amdgcn_mfma_f32_16x16x32_bf16((a), (b), (c), 0, 0, 0)

// LDS 163,088 B total (1 block/CU, 8 waves):
//  s_union 59,392 B: staging xhi/xlo[208][40]+wshi/wslo[128][40]  UNION  Phi/Plo[64][232]
//  s_k 33,280 B: Khi/Klo[208][40]   (K as [n][d])
//  s_q 10,240 B: Qhi/Qlo[64][40]
//  s_v 59,392 B: Vhi/Vlo[64][232]   (V as [vd][n], cols 196..223 zeroed)
//  bias_s 784 B
__global__ __launch_bounds__(512, 2)
void levit_fused_attn(const float* __restrict__ x,
                      const float* __restrict__ kv_w, const float* __restrict__ kv_g,
                      const float* __restrict__ kv_b, const float* __restrict__ kv_m,
                      const float* __restrict__ kv_v,
                      const float* __restrict__ q_w, const float* __restrict__ q_g,
                      const float* __restrict__ q_b, const float* __restrict__ q_m,
                      const float* __restrict__ q_v,
                      const float* __restrict__ attn_bias,
                      unsigned short* __restrict__ ao_hi,
                      unsigned short* __restrict__ ao_lo)
{
    __shared__ __align__(16) unsigned short s_union[29696];
    __shared__ __align__(16) unsigned short s_k[16640];
    __shared__ __align__(16) unsigned short s_q[5120];
    __shared__ __align__(16) unsigned short s_v[29696];
    __shared__ float bias_s[196];

    unsigned short* s_xhi  = s_union;              // [208][40]
    unsigned short* s_xlo  = s_union + 8320;
    unsigned short* s_wshi = s_union + 16640;      // [128][40]
    unsigned short* s_wslo = s_union + 21760;
    unsigned short* s_phi  = s_union;              // [64][232] (post-GEMM union)
    unsigned short* s_plo  = s_union + 14848;
    unsigned short* s_khi  = s_k;                  // [208][40]
    unsigned short* s_klo  = s_k + 8320;
    unsigned short* s_qhi  = s_q;                  // [64][40]
    unsigned short* s_qlo  = s_q + 2560;
    unsigned short* s_vhi  = s_v;                  // [64][232]
    unsigned short* s_vlo  = s_v + 14848;

    const int t = threadIdx.x;
    const int b = blockIdx.x;
    const int hh = blockIdx.y;

    const int l = t & 63;
    const int w = t >> 6;
    const int wr = w & 1;            // GEMM1 row-tile parity
    const int wc = w >> 1;           // GEMM1 col-tiles 2wc, 2wc+1
    const int lrow = l & 15;
    const int kg = (l >> 4) * 8;     // k offset within 32-chunk
    const int g4 = (l >> 4) * 4;     // C-layout row group
    const int nrt = 7 - wr;

    if (t < 196) bias_s[t] = attn_bias[hh * 196 + t];
    // zero V pad cols 196..223 (blocks NaN in PV: P=0 x V=junk)
    for (int i = t; i < 64 * 32; i += TB) {
        int row = i >> 5, c = 192 + (i & 31);
        if (c >= 196) { s_vhi[row * 232 + c] = 0; s_vlo[row * 232 + c] = 0; }
    }

    // ---------------- Merged GEMM (MFMA): [208 x 128] = x @ [kv_w; q_w]^T
    f32x4 acc[7][2];
    #pragma unroll
    for (int i = 0; i < 7; ++i) { acc[i][0] = (f32x4){0,0,0,0}; acc[i][1] = (f32x4){0,0,0,0}; }

    for (int kc = 0; kc < 256; kc += 32) {
        __syncthreads();
        #pragma unroll
        for (int i = 0; i < 4; ++i) {            // x: 208 rows x 8 float4
            int f = t + TB * i;
            if (f < 208 * 8) {
                int n = f >> 3, c4 = (f & 7) * 4;
                float4 v = {0.f, 0.f, 0.f, 0.f};
                if (n < 196) v = *(const float4*)&x[(b * 196 + n) * 256 + kc + c4];
                ushort4 vh, vl; split4(v, vh, vl);
                *(ushort4*)&s_xhi[n * 40 + c4] = vh;
                *(ushort4*)&s_xlo[n * 40 + c4] = vl;
            }
        }
        #pragma unroll
        for (int i = 0; i < 2; ++i) {            // w: 128 rows x 8 float4
            int f = t + TB * i;
            int j = f >> 3, c4 = (f & 7) * 4;
            const float* src = (j < 96) ? &kv_w[(hh * 96 + j) * 256 + kc + c4]
                                        : &q_w[(hh * 32 + j - 96) * 256 + kc + c4];
            float4 v = *(const float4*)src;
            ushort4 vh, vl; split4(v, vh, vl);
            *(ushort4*)&s_wshi[j * 40 + c4] = vh;
            *(ushort4*)&s_wslo[j * 40 + c4] = vl;
        }
        __syncthreads();

        bf16x8 bh0 = *(const bf16x8*)&s_wshi[(32 * wc + lrow) * 40 + kg];
        bf16x8 bl0 = *(const bf16x8*)&s_wslo[(32 * wc + lrow) * 40 + kg];
        bf16x8 bh1 = *(const bf16x8*)&s_wshi[(32 * wc + 16 + lrow) * 40 + kg];
        bf16x8 bl1 = *(const bf16x8*)&s_wslo[(32 * wc + 16 + lrow) * 40 + kg];
        #pragma unroll
        for (int rti = 0; rti < 7; ++rti) {
            if (rti < nrt) {
                int arow = 16 * (wr + 2 * rti) + lrow;
                bf16x8 ah = *(const bf16x8*)&s_xhi[arow * 40 + kg];
                bf16x8 al = *(const bf16x8*)&s_xlo[arow * 40 + kg];
                acc[rti][0] = MFMA16(ah, bh0, acc[rti][0]);
                acc[rti][0] = MFMA16(ah, bl0, acc[rti][0]);
                acc[rti][0] = MFMA16(al, bh0, acc[rti][0]);
                acc[rti][1] = MFMA16(ah, bh1, acc[rti][1]);
                acc[rti][1] = MFMA16(ah, bl1, acc[rti][1]);
                acc[rti][1] = MFMA16(al, bh1, acc[rti][1]);
            }
        }
    }

    // epilogue: norm, split-bf16, scatter to K[n][d] / vT[vd][n] / Q[qi][d]
    #pragma unroll
    for (int ct = 0; ct < 2; ++ct) {
        int ctg = 2 * wc + ct;
        int j = 16 * ctg + lrow;
        float gg, bb, mm, vv;
        if (ctg < 6) { int col = hh * 96 + j;        gg = kv_g[col]; bb = kv_b[col]; mm = kv_m[col]; vv = kv_v[col]; }
        else         { int col = hh * 32 + (j - 96); gg = q_g[col];  bb = q_b[col];  mm = q_m[col];  vv = q_v[col]; }
        float ivv = gg * rsqrtf(vv + EPS);
        float bee = bb - mm * ivv;
        #pragma unroll
        for (int rti = 0; rti < 7; ++rti) {
            if (rti < nrt) {
                int rt = wr + 2 * rti;
                #pragma unroll
                for (int reg = 0; reg < 4; ++reg) {
                    int n = 16 * rt + g4 + reg;
                    if (n < 196) {
                        float val = acc[rti][ct][reg] * ivv + bee;
                        unsigned short hi, lo; split1(val, hi, lo);
                        if (ctg < 2)      { s_khi[n * 40 + j] = hi; s_klo[n * 40 + j] = lo; }
                        else if (ctg < 6) { int vd = j - 32;
                                            s_vhi[vd * 232 + n] = hi; s_vlo[vd * 232 + n] = lo; }
                        else {
                            int a = n / 28, rem = n - 28 * a;
                            if (rem < 14 && !(rem & 1)) {
                                int qi = a * 7 + (rem >> 1);
                                s_qhi[qi * 40 + (j - 96)] = hi; s_qlo[qi * 40 + (j - 96)] = lo;
                            }
                        }
                    }
                }
            }
        }
    }
    __syncthreads();   // staging dead; K/Q/V ready

    // zero P pad cols 208..223
    for (int i = t; i < 64 * 16; i += TB) {
        int row = i >> 4, c = 208 + (i & 15);
        s_phi[row * 232 + c] = 0; s_plo[row * 232 + c] = 0;
    }

    // ---------------- QK + softmax (MFMA, waves 0..3; wave w owns M-tile mt=w)
    if (w < 4) {
        const int mt = w;
        bf16x8 qh = *(const bf16x8*)&s_qhi[(16 * mt + lrow) * 40 + kg];
        bf16x8 ql = *(const bf16x8*)&s_qlo[(16 * mt + lrow) * 40 + kg];
        f32x4 sv[13];
        #pragma unroll
        for (int nt = 0; nt < 13; ++nt) {
            bf16x8 kh = *(const bf16x8*)&s_khi[(16 * nt + lrow) * 40 + kg];
            bf16x8 kl = *(const bf16x8*)&s_klo[(16 * nt + lrow) * 40 + kg];
            f32x4 a = {0.f, 0.f, 0.f, 0.f};
            a = MFMA16(qh, kh, a);
            a = MFMA16(qh, kl, a);
            a = MFMA16(ql, kh, a);
            sv[nt] = a;
        }
        // mask + scale + bias; row stats per reg (row = 16mt + g4 + reg, col = 16nt + lrow)
        const int m_base = 16 * mt + g4;
        float lmax[4] = {-3.0e38f, -3.0e38f, -3.0e38f, -3.0e38f};
        #pragma unroll
        for (int reg = 0; reg < 4; ++reg) {
            int m = m_base + reg;
            int mq = m < 49 ? m : 48;                 // clamp junk rows for bias idx
            int yq = (mq / 7) * 2, xq2 = (mq % 7) * 2;
            #pragma unroll
            for (int nt = 0; nt < 13; ++nt) {
                int n = 16 * nt + lrow;
                float s;
                if (n < 196) {
                    int yk = n / 14, xk = n - 14 * yk;
                    int r0 = yq >= yk ? yq - yk : yk - yq;
                    int r1 = xq2 >= xk ? xq2 - xk : xk - xq2;
                    s = sv[nt][reg] * QK_SCALE + bias_s[r0 * 14 + r1];
                } else {
                    s = -1.0e30f;
                }
                sv[nt][reg] = s;
                lmax[reg] = fmaxf(lmax[reg], s);
            }
        }
        #pragma unroll
        for (int off = 1; off < 16; off <<= 1) {
            #pragma unroll
            for (int reg = 0; reg < 4; ++reg)
                lmax[reg] = fmaxf(lmax[reg], __shfl_xor(lmax[reg], off, 64));
        }
        float rsum[4] = {0.f, 0.f, 0.f, 0.f};
        #pragma unroll
        for (int nt = 0; nt < 13; ++nt) {
            #pragma unroll
            for (int reg = 0; reg < 4; ++reg) {
                float p = __expf(sv[nt][reg] - lmax[reg]);
                sv[nt][reg] = p;
                rsum[reg] += p;
            }
        }
        #pragma unroll
        for (int off = 1; off < 16; off <<= 1) {
            #pragma unroll
            for (int reg = 0; reg < 4; ++reg)
                rsum[reg] += __shfl_xor(rsum[reg], off, 64);
        }
        float rinv[4];
        #pragma unroll
        for (int reg = 0; reg < 4; ++reg) rinv[reg] = 1.f / rsum[reg];
        // normalized P -> LDS (split bf16)
        #pragma unroll
        for (int nt = 0; nt < 13; ++nt) {
            #pragma unroll
            for (int reg = 0; reg < 4; ++reg) {
                float pn = sv[nt][reg] * rinv[reg];
                unsigned short hi, lo; split1(pn, hi, lo);
                int row = m_base + reg, col = 16 * nt + lrow;
                s_phi[row * 232 + col] = hi;
                s_plo[row * 232 + col] = lo;
            }
        }
    }
    __syncthreads();   // P ready

    // ---------------- PV (MFMA, all 8 waves; wave: mt = w&3, ntv = 2*(w>>2)+{0,1})
    {
        const int mtv = w & 3;
        const int half = w >> 2;
        f32x4 pacc[2] = {{0.f,0.f,0.f,0.f},{0.f,0.f,0.f,0.f}};
        #pragma unroll
        for (int s = 0; s < 7; ++s) {
            bf16x8 ph = *(const bf16x8*)&s_phi[(16 * mtv + lrow) * 232 + 32 * s + kg];
            bf16x8 pl = *(const bf16x8*)&s_plo[(16 * mtv + lrow) * 232 + 32 * s + kg];
            #pragma unroll
            for (int i = 0; i < 2; ++i) {
                int ntv = 2 * half + i;
                bf16x8 vh = *(const bf16x8*)&s_vhi[(16 * ntv + lrow) * 232 + 32 * s + kg];
                bf16x8 vl = *(const bf16x8*)&s_vlo[(16 * ntv + lrow) * 232 + 32 * s + kg];
                pacc[i] = MFMA16(ph, vh, pacc[i]);
                pacc[i] = MFMA16(ph, vl, pacc[i]);
                pacc[i] = MFMA16(pl, vh, pacc[i]);
            }
        }
        // epilogue: hardswish + split-bf16 -> ws (ao_hi/ao_lo)
        #pragma unroll
        for (int i = 0; i < 2; ++i) {
            int vd = 16 * (2 * half + i) + lrow;
            #pragma unroll
            for (int reg = 0; reg < 4; ++reg) {
                int r = 16 * mtv + g4 + reg;
                if (r < 49) {
                    float v = pacc[i][reg];
                    float hs = v * fminf(fmaxf(v + 3.f, 0.f), 6.f) * (1.f / 6.f);
                    unsigned short hi, lo; split1(hs, hi, lo);
                    int idx = ((b * 49 + r) * 8 + hh) * 64 + vd;
                    ao_hi[idx] = hi;
                    ao_lo[idx] = lo;
                }
            }
        }
    }
}

// out = linear_norm(hs_pre_split(A), proj_w): block = (b, 96-col group), MFMA
__global__ __launch_bounds__(512, 2)
void levit_proj(const unsigned short* __restrict__ ao_hi,
                const unsigned short* __restrict__ ao_lo,
                const float* __restrict__ pw, const float* __restrict__ pg,
                const float* __restrict__ pb, const float* __restrict__ pm,
                const float* __restrict__ pv,
                float* __restrict__ out)
{
    __shared__ __align__(16) unsigned short s_ahi[2560];   // [64][40]
    __shared__ __align__(16) unsigned short s_alo[2560];
    __shared__ __align__(16) unsigned short s_whi[3840];   // [96][40]
    __shared__ __align__(16) unsigned short s_wlo[3840];

    const int t = threadIdx.x;
    const int b = blockIdx.x;
    const int cg = blockIdx.y;       // 96-col group (0..3)
    const int l = t & 63;
    const int w = t >> 6;
    const int lrow = l & 15;
    const int kg = (l >> 4) * 8;
    const int g4 = (l >> 4) * 4;

    f32x4 acc[3] = {{0.f,0.f,0.f,0.f},{0.f,0.f,0.f,0.f},{0.f,0.f,0.f,0.f}};

    for (int kc = 0; kc < 512; kc += 32) {
        __syncthreads();
        {                                         // A: 2 bufs x 64 rows x 4 b128 = 512
            int buf = t >> 8, rem = t & 255;
            int r = rem >> 2, c8 = (rem & 3) * 8;
            const unsigned short* src = buf ? ao_lo : ao_hi;
            unsigned short* dst = buf ? s_alo : s_ahi;
            bf16x8 v = {};
            if (r < 49) v = *(const bf16x8*)&src[(b * 49 + r) * 512 + kc + c8];
            *(bf16x8*)&dst[r * 40 + c8] = v;
        }
        for (int f = t; f < 96 * 8; f += TB) {    // W: 96 rows x 8 f4, split
            int r = f >> 3, c4 = (f & 7) * 4;
            float4 v = *(const float4*)&pw[(cg * 96 + r) * 512 + kc + c4];
            ushort4 vh, vl; split4(v, vh, vl);
            *(ushort4*)&s_whi[r * 40 + c4] = vh;
            *(ushort4*)&s_wlo[r * 40 + c4] = vl;
        }
        __syncthreads();
        #pragma unroll
        for (int i = 0; i < 3; ++i) {             // 24 tiles, 3 per wave
            int tid3 = 3 * w + i;
            int mt = tid3 & 3, nt = tid3 >> 2;
            bf16x8 ah = *(const bf16x8*)&s_ahi[(16 * mt + lrow) * 40 + kg];
            bf16x8 al = *(const bf16x8*)&s_alo[(16 * mt + lrow) * 40 + kg];
            bf16x8 bh = *(const bf16x8*)&s_whi[(16 * nt + lrow) * 40 + kg];
            bf16x8 bl = *(const bf16x8*)&s_wlo[(16 * nt + lrow) * 40 + kg];
            acc[i] = MFMA16(ah, bh, acc[i]);
            acc[i] = MFMA16(ah, bl, acc[i]);
            acc[i] = MFMA16(al, bh, acc[i]);
        }
    }

    #pragma unroll
    for (int i = 0; i < 3; ++i) {
        int tid3 = 3 * w + i;
        int mt = tid3 & 3, nt = tid3 >> 2;
        int o = cg * 96 + 16 * nt + lrow;
        float iv = pg[o] * rsqrtf(pv[o] + EPS);
        float be = pb[o] - pm[o] * iv;
        #pragma unroll
        for (int reg = 0; reg < 4; ++reg) {
            int r = 16 * mt + g4 + reg;
            if (r < 49) out[(b * 49 + r) * 384 + o] = acc[i][reg] * iv + be;
        }
    }
}

extern "C" void kernel_launch(void* const* d_in, const int* in_sizes, int n_in,
                              void* d_out, int out_size, void* d_ws, size_t ws_size,
                              hipStream_t stream) {
    const float* x     = (const float*)d_in[0];
    const float* kv_w  = (const float*)d_in[1];
    const float* kv_g  = (const float*)d_in[2];
    const float* kv_b  = (const float*)d_in[3];
    const float* kv_m  = (const float*)d_in[4];
    const float* kv_v  = (const float*)d_in[5];
    const float* q_w   = (const float*)d_in[6];
    const float* q_g   = (const float*)d_in[7];
    const float* q_b   = (const float*)d_in[8];
    const float* q_m   = (const float*)d_in[9];
    const float* q_v   = (const float*)d_in[10];
    const float* pw    = (const float*)d_in[11];
    const float* pg    = (const float*)d_in[12];
    const float* pb    = (const float*)d_in[13];
    const float* pm    = (const float*)d_in[14];
    const float* pv    = (const float*)d_in[15];
    const float* ab    = (const float*)d_in[16];

    // ws: ao split-bf16 (hardswish pre-applied): 2 x 12544*512 ushort = 25.7 MB
    unsigned short* ao_hi = (unsigned short*)d_ws;
    unsigned short* ao_lo = ao_hi + 12544 * 512;

    dim3 g1(256, 8);
    levit_fused_attn<<<g1, TB, 0, stream>>>(x, kv_w, kv_g, kv_b, kv_m, kv_v,
                                            q_w, q_g, q_b, q_m, q_v, ab, ao_hi, ao_lo);
    levit_proj<<<dim3(256, 4), TB, 0, stream>>>(ao_hi, ao_lo, pw, pg, pb, pm, pv,
                                                (float*)d_out);
}